// Round 3
// baseline (1035.453 us; speedup 1.0000x reference)
//
#include <hip/hip_runtime.h>

#define D128 128

typedef __attribute__((ext_vector_type(8))) short bf16x8;
typedef __attribute__((ext_vector_type(4))) float f32x4;
typedef unsigned short u16;

__device__ __forceinline__ u16 f2b(float f) {
  union { float f; unsigned int u; } x; x.f = f;
  unsigned int r = x.u + 0x7fffu + ((x.u >> 16) & 1u);
  return (u16)(r >> 16);
}

// ---------------- fused conversions + zeroing ----------------
// ranges: [0,n4c) chem f32->bf16 (float4), [.,+n4p) protein, [.,+wq) Wcat quads,
// [.,+zq) zero int4 over deg+cur arrays.

__global__ __launch_bounds__(256) void cvt_all_k(const float* __restrict__ xc, const float* __restrict__ xp,
                                                 const float* __restrict__ Wl, const float* __restrict__ Wr,
                                                 u16* __restrict__ xcb, u16* __restrict__ xpb,
                                                 u16* __restrict__ Wcat, int* __restrict__ zbase,
                                                 int n4c, int n4p, int wq, int zq) {
  int TOT = n4c + n4p + wq + zq;
  for (int i = blockIdx.x * 256 + threadIdx.x; i < TOT; i += gridDim.x * 256) {
    if (i < n4c + n4p) {
      const float* src = (i < n4c) ? xc : xp;
      u16* dst = (i < n4c) ? xcb : xpb;
      int q = (i < n4c) ? i : (i - n4c);
      float4 f = ((const float4*)src)[q];
      uint2 u;
      u.x = (unsigned)f2b(f.x) | ((unsigned)f2b(f.y) << 16);
      u.y = (unsigned)f2b(f.z) | ((unsigned)f2b(f.w) << 16);
      ((uint2*)dst)[q] = u;
    } else if (i < n4c + n4p + wq) {
      int t = (i - n4c - n4p) * 4;
      int slice = t >> 15;
      int j = (t >> 8) & 127;
      int k = t & 255;
      const float* sw = (k < 128) ? (Wl + (size_t)slice * 16384 + j * 128 + k)
                                  : (Wr + (size_t)slice * 16384 + j * 128 + (k - 128));
      float4 f = *(const float4*)sw;
      uint2 u;
      u.x = (unsigned)f2b(f.x) | ((unsigned)f2b(f.y) << 16);
      u.y = (unsigned)f2b(f.z) | ((unsigned)f2b(f.w) << 16);
      *(uint2*)&Wcat[t] = u;
    } else {
      int z = i - n4c - n4p - wq;
      int4 zv; zv.x = 0; zv.y = 0; zv.z = 0; zv.w = 0;
      ((int4*)zbase)[z] = zv;
    }
  }
}

// ---------------- combined CSR build ----------------
// node space: protein [0,NP), chem [NP,NP+NC). adj is one 2E array.

__global__ __launch_bounds__(256) void degree_k(const int* __restrict__ src, const int* __restrict__ dst,
                                                int* deg, int NP, int E) {
  int e = blockIdx.x * 256 + threadIdx.x;
  if (e >= E) return;
  atomicAdd(&deg[dst[e]], 1);
  atomicAdd(&deg[NP + src[e]], 1);
}

__global__ __launch_bounds__(256) void scan1_k(const int* __restrict__ in, int* __restrict__ out,
                                               int* __restrict__ bsum, int n) {
  __shared__ int sh[256];
  int tid = threadIdx.x;
  int base = blockIdx.x * 2048 + tid * 8;
  int v[8]; int s = 0;
#pragma unroll
  for (int u = 0; u < 8; ++u) { int i = base + u; v[u] = (i < n) ? in[i] : 0; s += v[u]; }
  sh[tid] = s; __syncthreads();
#pragma unroll
  for (int o = 1; o < 256; o <<= 1) {
    int t = (tid >= o) ? sh[tid - o] : 0;
    __syncthreads();
    sh[tid] += t;
    __syncthreads();
  }
  int run = sh[tid] - s;
  if (tid == 255) bsum[blockIdx.x] = sh[255];
#pragma unroll
  for (int u = 0; u < 8; ++u) { int i = base + u; if (i < n) out[i] = run; run += v[u]; }
}

__global__ void scan_small_k(int* b, int n) {
  __shared__ int sh[64];
  int tid = threadIdx.x;
  int v = (tid < n) ? b[tid] : 0;
  sh[tid] = v; __syncthreads();
  for (int o = 1; o < 64; o <<= 1) {
    int t = (tid >= o) ? sh[tid - o] : 0;
    __syncthreads();
    sh[tid] += t;
    __syncthreads();
  }
  if (tid < n) b[tid] = sh[tid] - v;
}

__global__ __launch_bounds__(256) void scan_add_k(int* out, const int* __restrict__ bsum, int n) {
  int b = blockIdx.x;
  if (b == 0) return;
  int add = bsum[b];
  int base = b * 2048;
  for (int i = threadIdx.x; i < 2048; i += 256) { int idx = base + i; if (idx < n) out[idx] += add; }
}

__global__ __launch_bounds__(256) void fill_k(const int* __restrict__ src, const int* __restrict__ dst,
                                              const int* __restrict__ off, int* cur, int* adj,
                                              int NP, int E) {
  int e = blockIdx.x * 256 + threadIdx.x;
  if (e >= E) return;
  int s = src[e], d = dst[e];
  int pp = atomicAdd(&cur[d], 1); adj[off[d] + pp] = s;
  int pc = atomicAdd(&cur[NP + s], 1); adj[off[NP + s] + pc] = d;
}

// ---------------- fused layer: agg-mean -> LDS -> MFMA GEMM -> relu -> out ----------------
// block = 256 threads (4 waves), 128-row output tile. Blocks [0,tilesP) do protein side,
// [tilesP, tilesP+tilesC) chem side. A(mean) built in LDS (XOR-swizzled); A(hold) and
// B(Wcat) fragments read directly from global (L1/L2-hot).

__global__ __launch_bounds__(256) void layer_k(const u16* __restrict__ hc, const u16* __restrict__ hp,
                                               u16* __restrict__ nc, u16* __restrict__ np_,
                                               const int* __restrict__ adj, const int* __restrict__ off,
                                               const int* __restrict__ deg,
                                               const u16* __restrict__ Wcat_l, const float* __restrict__ bl_l,
                                               int NP, int NC, int tilesP) {
  __shared__ u16 Am[128 * 128];
  const int b = blockIdx.x;
  const bool isP = b < tilesP;
  const int rbase = (isP ? b : b - tilesP) * 128;
  const u16* __restrict__ srcH = isP ? hc : hp;    // neighbor features
  const u16* __restrict__ holdH = isP ? hp : hc;   // self features
  u16* __restrict__ outH = isP ? np_ : nc;
  const u16* __restrict__ W = Wcat_l + (isP ? 0 : 128 * 256);
  const float* __restrict__ bias = bl_l + (isP ? 0 : 128);
  const int N = isP ? NP : NC;
  const int obase = isP ? 0 : NP;

  const int tid = threadIdx.x;
  const int w = tid >> 6, lane = tid & 63;

  // ---- phase 1: neighbor mean into Am, swizzled bf16 ----
  {
    const int half = lane >> 5;          // k-col >= 64?
    const int c = (lane >> 2) & 7;       // chunk within 64-col half
    const int p2 = (lane & 3) * 2;       // ushort offset within 16B chunk
    const int l2 = lane * 2;             // k columns 2l, 2l+1
    for (int rr = w; rr < 128; rr += 4) {
      int v = rbase + rr; if (v >= N) v = N - 1;
      int s = off[obase + v], cnt = deg[obase + v];
      float ax = 0.f, ay = 0.f, bx = 0.f, by = 0.f;
      int n = 0;
      for (; n + 2 <= cnt; n += 2) {
        int i0 = adj[s + n], i1 = adj[s + n + 1];
        unsigned u0 = *(const unsigned*)&srcH[(size_t)i0 * D128 + l2];
        unsigned u1 = *(const unsigned*)&srcH[(size_t)i1 * D128 + l2];
        ax += __uint_as_float(u0 << 16); ay += __uint_as_float(u0 & 0xffff0000u);
        bx += __uint_as_float(u1 << 16); by += __uint_as_float(u1 & 0xffff0000u);
      }
      if (n < cnt) {
        int i0 = adj[s + n];
        unsigned u0 = *(const unsigned*)&srcH[(size_t)i0 * D128 + l2];
        ax += __uint_as_float(u0 << 16); ay += __uint_as_float(u0 & 0xffff0000u);
      }
      float inv = (cnt > 0) ? 1.f / (float)cnt : 0.f;
      unsigned pk = (unsigned)f2b((ax + bx) * inv) | ((unsigned)f2b((ay + by) * inv) << 16);
      *(unsigned*)&Am[rr * 128 + half * 64 + (((c ^ (rr & 7)) << 3)) + p2] = pk;
    }
  }
  __syncthreads();

  // ---- phase 2: GEMM ----
  const int wr = w >> 1, wc = w & 1;
  const int l15 = lane & 15, chi = lane >> 4;
  f32x4 acc[4][4];
#pragma unroll
  for (int m = 0; m < 4; ++m)
#pragma unroll
    for (int n = 0; n < 4; ++n) acc[m][n] = (f32x4){0.f, 0.f, 0.f, 0.f};

#pragma unroll
  for (int ks = 0; ks < 4; ++ks) {
#pragma unroll
    for (int kk = 0; kk < 2; ++kk) {
      bf16x8 a[4], bf[4];
#pragma unroll
      for (int m = 0; m < 4; ++m) {
        const int row = wr * 64 + m * 16 + l15;
        if (ks < 2) {
          a[m] = *(const bf16x8*)&Am[row * 128 + ks * 64 + (((kk * 4 + chi) ^ (row & 7)) << 3)];
        } else {
          int rg = rbase + row; if (rg >= N) rg = N - 1;
          a[m] = *(const bf16x8*)&holdH[(size_t)rg * D128 + (ks - 2) * 64 + kk * 32 + chi * 8];
        }
      }
#pragma unroll
      for (int n = 0; n < 4; ++n) {
        const int j = wc * 64 + n * 16 + l15;
        bf[n] = *(const bf16x8*)&W[j * 256 + ks * 64 + kk * 32 + chi * 8];
      }
#pragma unroll
      for (int m = 0; m < 4; ++m)
#pragma unroll
        for (int n = 0; n < 4; ++n)
          acc[m][n] = __builtin_amdgcn_mfma_f32_16x16x32_bf16(a[m], bf[n], acc[m][n], 0, 0, 0);
    }
  }

  // ---- epilogue: bias + relu + bf16 store ----
#pragma unroll
  for (int n = 0; n < 4; ++n) {
    const int col = wc * 64 + n * 16 + l15;
    const float bv = bias[col];
#pragma unroll
    for (int m = 0; m < 4; ++m) {
      const int rb2 = rbase + wr * 64 + m * 16 + chi * 4;
#pragma unroll
      for (int q = 0; q < 4; ++q) {
        const int row = rb2 + q;
        if (row < N) {
          float vv = acc[m][n][q] + bv;
          vv = vv > 0.f ? vv : 0.f;
          outH[(size_t)row * D128 + col] = f2b(vv);
        }
      }
    }
  }
}

// ---------------- decoder ----------------

__global__ __launch_bounds__(256) void decoder_b_k(const u16* __restrict__ hc, const u16* __restrict__ hp,
                                                   const int* __restrict__ row, const int* __restrict__ col,
                                                   const float* __restrict__ Wd, const float* __restrict__ bd,
                                                   float* __restrict__ out, int EL) {
  int e = blockIdx.x * 4 + (threadIdx.x >> 6);
  if (e >= EL) return;
  int lane = threadIdx.x & 63;
  int l2 = lane * 2;
  int r = row[e], c = col[e];
  unsigned ua = *(const unsigned*)&hc[(size_t)r * D128 + l2];
  unsigned ub = *(const unsigned*)&hp[(size_t)c * D128 + l2];
  float ax = __uint_as_float(ua << 16), ay = __uint_as_float(ua & 0xffff0000u);
  float bx = __uint_as_float(ub << 16), by = __uint_as_float(ub & 0xffff0000u);
  float2 w0 = *(const float2*)&Wd[l2];
  float2 w1 = *(const float2*)&Wd[128 + l2];
  float p = ax * w0.x + ay * w0.y + bx * w1.x + by * w1.y;
#pragma unroll
  for (int m = 1; m < 64; m <<= 1) p += __shfl_xor(p, m, 64);
  float* xo = out + EL + (size_t)e * 256;
  float2 A; A.x = ax; A.y = ay;
  float2 B; B.x = bx; B.y = by;
  *(float2*)&xo[l2] = A;
  *(float2*)&xo[128 + l2] = B;
  if (lane == 0) out[e] = p + bd[0];
}

// ---------------- host ----------------

extern "C" void kernel_launch(void* const* d_in, const int* in_sizes, int n_in,
                              void* d_out, int out_size, void* d_ws, size_t ws_size,
                              hipStream_t stream) {
  const float* x_chem = (const float*)d_in[0];
  const float* x_prot = (const float*)d_in[1];
  const float* Wl = (const float*)d_in[2];
  const float* bl = (const float*)d_in[3];
  const float* Wr = (const float*)d_in[4];
  const float* Wd = (const float*)d_in[5];
  const float* bd = (const float*)d_in[6];
  const int* src = (const int*)d_in[7];
  const int* dst = (const int*)d_in[8];
  const int* row = (const int*)d_in[9];
  const int* col = (const int*)d_in[10];

  int NC = in_sizes[0] / D128;
  int NP = in_sizes[1] / D128;
  int E  = in_sizes[7];
  int EL = in_sizes[9];
  float* out = (float*)d_out;
  int NT = NP + NC;

  // workspace layout
  char* w = (char*)d_ws;
  size_t szC = (size_t)NC * D128 * 2;
  size_t szP = (size_t)NP * D128 * 2;
  u16* xc_bf = (u16*)w; w += szC;
  u16* xp_bf = (u16*)w; w += szP;
  u16* bufC0 = (u16*)w; w += szC;
  u16* bufC1 = (u16*)w; w += szC;
  u16* bufP0 = (u16*)w; w += szP;
  u16* bufP1 = (u16*)w; w += szP;
  u16* Wcat  = (u16*)w; w += (size_t)6 * 128 * 256 * 2;
  int* deg = (int*)w; w += (size_t)NT * 4;   // deg+cur contiguous for fused zeroing
  int* cur = (int*)w; w += (size_t)NT * 4;
  int* off = (int*)w; w += (size_t)NT * 4;
  int* bs  = (int*)w; w += 64 * 4;
  int* adj = (int*)w; w += (size_t)2 * E * 4;
  if ((size_t)(w - (char*)d_ws) > ws_size) return;

  // fused conversions + zeroing (deg+cur = 2*NT ints)
  int n4c = NC * D128 / 4, n4p = NP * D128 / 4;
  int wq = 6 * 128 * 256 / 4;
  int zq = 2 * NT / 4;
  cvt_all_k<<<2048, 256, 0, stream>>>(x_chem, x_prot, Wl, Wr, xc_bf, xp_bf, Wcat, deg,
                                      n4c, n4p, wq, zq);

  // CSR build (combined node space)
  int gE = (E + 255) / 256;
  degree_k<<<gE, 256, 0, stream>>>(src, dst, deg, NP, E);
  int nb = (NT + 2047) / 2048;
  scan1_k<<<nb, 256, 0, stream>>>(deg, off, bs, NT);
  scan_small_k<<<1, 64, 0, stream>>>(bs, nb);
  scan_add_k<<<nb, 256, 0, stream>>>(off, bs, NT);
  fill_k<<<gE, 256, 0, stream>>>(src, dst, off, cur, adj, NP, E);

  int tilesP = (NP + 127) / 128;
  int tilesC = (NC + 127) / 128;
  const u16* hc = xc_bf;
  const u16* hp = xp_bf;
  for (int l = 0; l < 3; ++l) {
    u16* nc  = (l & 1) ? bufC1 : bufC0;
    u16* np_ = (l & 1) ? bufP1 : bufP0;
    const u16* Wc_l = Wcat + (size_t)(l * 2) * 128 * 256;
    const float* bl_l = bl + (size_t)(l * 2) * D128;
    layer_k<<<tilesP + tilesC, 256, 0, stream>>>(hc, hp, nc, np_, adj, off, deg,
                                                 Wc_l, bl_l, NP, NC, tilesP);
    hc = nc; hp = np_;
  }

  decoder_b_k<<<(EL + 3) / 4, 256, 0, stream>>>(hc, hp, row, col, Wd, bd, out, EL);
}

// Round 4
// 486.789 us; speedup vs baseline: 2.1271x; 2.1271x over previous
//
#include <hip/hip_runtime.h>

#define D128 128

typedef __attribute__((ext_vector_type(8))) short bf16x8;
typedef __attribute__((ext_vector_type(4))) float f32x4;
typedef unsigned short u16;

__device__ __forceinline__ u16 f2b(float f) {
  union { float f; unsigned int u; } x; x.f = f;
  unsigned int r = x.u + 0x7fffu + ((x.u >> 16) & 1u);
  return (u16)(r >> 16);
}

#define GLD16(gp, lp) __builtin_amdgcn_global_load_lds( \
    (const __attribute__((address_space(1))) void*)(gp), \
    (__attribute__((address_space(3))) void*)(lp), 16, 0, 0)

// ---------------- fused conversions + zeroing ----------------

__global__ __launch_bounds__(256) void cvt_all_k(const float* __restrict__ xc, const float* __restrict__ xp,
                                                 const float* __restrict__ Wl, const float* __restrict__ Wr,
                                                 u16* __restrict__ xcb, u16* __restrict__ xpb,
                                                 u16* __restrict__ Wcat, int* __restrict__ zbase,
                                                 int n4c, int n4p, int wq, int zq) {
  int TOT = n4c + n4p + wq + zq;
  for (int i = blockIdx.x * 256 + threadIdx.x; i < TOT; i += gridDim.x * 256) {
    if (i < n4c + n4p) {
      const float* src = (i < n4c) ? xc : xp;
      u16* dst = (i < n4c) ? xcb : xpb;
      int q = (i < n4c) ? i : (i - n4c);
      float4 f = ((const float4*)src)[q];
      uint2 u;
      u.x = (unsigned)f2b(f.x) | ((unsigned)f2b(f.y) << 16);
      u.y = (unsigned)f2b(f.z) | ((unsigned)f2b(f.w) << 16);
      ((uint2*)dst)[q] = u;
    } else if (i < n4c + n4p + wq) {
      int t = (i - n4c - n4p) * 4;
      int slice = t >> 15;
      int j = (t >> 8) & 127;
      int k = t & 255;
      const float* sw = (k < 128) ? (Wl + (size_t)slice * 16384 + j * 128 + k)
                                  : (Wr + (size_t)slice * 16384 + j * 128 + (k - 128));
      float4 f = *(const float4*)sw;
      uint2 u;
      u.x = (unsigned)f2b(f.x) | ((unsigned)f2b(f.y) << 16);
      u.y = (unsigned)f2b(f.z) | ((unsigned)f2b(f.w) << 16);
      *(uint2*)&Wcat[t] = u;
    } else {
      int z = i - n4c - n4p - wq;
      int4 zv; zv.x = 0; zv.y = 0; zv.z = 0; zv.w = 0;
      ((int4*)zbase)[z] = zv;
    }
  }
}

// ---------------- combined CSR build ----------------

__global__ __launch_bounds__(256) void degree_k(const int* __restrict__ src, const int* __restrict__ dst,
                                                int* deg, int NP, int E) {
  int e = blockIdx.x * 256 + threadIdx.x;
  if (e >= E) return;
  atomicAdd(&deg[dst[e]], 1);
  atomicAdd(&deg[NP + src[e]], 1);
}

__global__ __launch_bounds__(256) void scan1_k(const int* __restrict__ in, int* __restrict__ out,
                                               int* __restrict__ bsum, int n) {
  __shared__ int sh[256];
  int tid = threadIdx.x;
  int base = blockIdx.x * 2048 + tid * 8;
  int v[8]; int s = 0;
#pragma unroll
  for (int u = 0; u < 8; ++u) { int i = base + u; v[u] = (i < n) ? in[i] : 0; s += v[u]; }
  sh[tid] = s; __syncthreads();
#pragma unroll
  for (int o = 1; o < 256; o <<= 1) {
    int t = (tid >= o) ? sh[tid - o] : 0;
    __syncthreads();
    sh[tid] += t;
    __syncthreads();
  }
  int run = sh[tid] - s;
  if (tid == 255) bsum[blockIdx.x] = sh[255];
#pragma unroll
  for (int u = 0; u < 8; ++u) { int i = base + u; if (i < n) out[i] = run; run += v[u]; }
}

__global__ void scan_small_k(int* b, int n) {
  __shared__ int sh[64];
  int tid = threadIdx.x;
  int v = (tid < n) ? b[tid] : 0;
  sh[tid] = v; __syncthreads();
  for (int o = 1; o < 64; o <<= 1) {
    int t = (tid >= o) ? sh[tid - o] : 0;
    __syncthreads();
    sh[tid] += t;
    __syncthreads();
  }
  if (tid < n) b[tid] = sh[tid] - v;
}

__global__ __launch_bounds__(256) void scan_add_k(int* out, const int* __restrict__ bsum, int n) {
  int b = blockIdx.x;
  if (b == 0) return;
  int add = bsum[b];
  int base = b * 2048;
  for (int i = threadIdx.x; i < 2048; i += 256) { int idx = base + i; if (idx < n) out[idx] += add; }
}

__global__ __launch_bounds__(256) void fill_k(const int* __restrict__ src, const int* __restrict__ dst,
                                              const int* __restrict__ off, int* cur, int* adj,
                                              int NP, int E) {
  int e = blockIdx.x * 256 + threadIdx.x;
  if (e >= E) return;
  int s = src[e], d = dst[e];
  int pp = atomicAdd(&cur[d], 1); adj[off[d] + pp] = s;
  int pc = atomicAdd(&cur[NP + s], 1); adj[off[NP + s] + pc] = d;
}

// ---------------- aggregation: both sides, one wave per node ----------------
// Stage up to 64 neighbor indices via one coalesced load, __shfl-broadcast them,
// then 4 independent row-gathers in flight per iteration.

__global__ __launch_bounds__(256) void agg_all_k(const u16* __restrict__ hc, const u16* __restrict__ hp,
                                                 u16* __restrict__ meanC, u16* __restrict__ meanP,
                                                 const int* __restrict__ adj, const int* __restrict__ off,
                                                 const int* __restrict__ deg, int NP, int NT) {
  int v = blockIdx.x * 4 + (threadIdx.x >> 6);
  if (v >= NT) return;
  int lane = threadIdx.x & 63;
  bool isP = v < NP;
  const u16* __restrict__ src = isP ? hc : hp;
  u16* outm = isP ? (meanP + (size_t)v * D128) : (meanC + (size_t)(v - NP) * D128);
  int s = off[v], cnt = deg[v];
  int l2 = lane * 2;
  float a0x = 0.f, a0y = 0.f, a1x = 0.f, a1y = 0.f;
  float a2x = 0.f, a2y = 0.f, a3x = 0.f, a3y = 0.f;
  int n = 0;
  while (n < cnt) {
    int batch = cnt - n; if (batch > 64) batch = 64;
    int idx = (lane < batch) ? adj[s + n + lane] : 0;
    int j = 0;
    for (; j + 4 <= batch; j += 4) {
      int i0 = __shfl(idx, j);
      int i1 = __shfl(idx, j + 1);
      int i2 = __shfl(idx, j + 2);
      int i3 = __shfl(idx, j + 3);
      unsigned u0 = *(const unsigned*)&src[(size_t)i0 * D128 + l2];
      unsigned u1 = *(const unsigned*)&src[(size_t)i1 * D128 + l2];
      unsigned u2 = *(const unsigned*)&src[(size_t)i2 * D128 + l2];
      unsigned u3 = *(const unsigned*)&src[(size_t)i3 * D128 + l2];
      a0x += __uint_as_float(u0 << 16); a0y += __uint_as_float(u0 & 0xffff0000u);
      a1x += __uint_as_float(u1 << 16); a1y += __uint_as_float(u1 & 0xffff0000u);
      a2x += __uint_as_float(u2 << 16); a2y += __uint_as_float(u2 & 0xffff0000u);
      a3x += __uint_as_float(u3 << 16); a3y += __uint_as_float(u3 & 0xffff0000u);
    }
    for (; j < batch; ++j) {
      int i0 = __shfl(idx, j);
      unsigned u0 = *(const unsigned*)&src[(size_t)i0 * D128 + l2];
      a0x += __uint_as_float(u0 << 16); a0y += __uint_as_float(u0 & 0xffff0000u);
    }
    n += batch;
  }
  float sx = (a0x + a1x) + (a2x + a3x);
  float sy = (a0y + a1y) + (a2y + a3y);
  float inv = (cnt > 0) ? 1.f / (float)cnt : 0.f;
  unsigned pk = (unsigned)f2b(sx * inv) | ((unsigned)f2b(sy * inv) << 16);
  *(unsigned*)&outm[l2] = pk;
}

// ---------------- MFMA GEMM, both sides: io = relu(concat(io,hold) @ Wcat^T + b) ----------------
// round-2 proven structure: 128x128 tile, K=256 in 4 steps of 64, global_load_lds
// staging with pre-swizzled source (chunk ^= row&7), 4 waves (2x2), 16x16x32 bf16 MFMA.

__global__ __launch_bounds__(256) void gemm_both_k(u16* __restrict__ np_, u16* __restrict__ nc,
                                                   const u16* __restrict__ hp, const u16* __restrict__ hc,
                                                   const u16* __restrict__ Wcat_l, const float* __restrict__ bl_l,
                                                   int NP, int NC, int tilesP) {
  __shared__ u16 As[128 * 64];
  __shared__ u16 Bs[128 * 64];
  const int b = blockIdx.x;
  const bool isP = b < tilesP;
  const int rbase = (isP ? b : b - tilesP) * 128;
  u16* __restrict__ io_mean = isP ? np_ : nc;
  const u16* __restrict__ hold = isP ? hp : hc;
  const u16* __restrict__ Wcat = Wcat_l + (isP ? 0 : 128 * 256);
  const float* __restrict__ bias = bl_l + (isP ? 0 : 128);
  const int N = isP ? NP : NC;

  const int tid = threadIdx.x;
  const int w = tid >> 6, lane = tid & 63;
  const int wr = w >> 1, wc = w & 1;
  const int l15 = lane & 15, chi = lane >> 4;

  f32x4 acc[4][4];
#pragma unroll
  for (int m = 0; m < 4; ++m)
#pragma unroll
    for (int n = 0; n < 4; ++n) acc[m][n] = (f32x4){0.f, 0.f, 0.f, 0.f};

  for (int ks = 0; ks < 4; ++ks) {
    const int k0 = ks * 64;
    const u16* Xsrc = (k0 < 128) ? io_mean : hold;
    const int kb = k0 & 127;
    if (ks) __syncthreads();
#pragma unroll
    for (int q = 0; q < 4; ++q) {
      const int ibase = w * 256 + q * 64;
      const int i = ibase + lane;
      const int r = i >> 3;
      const int cg = (i & 7) ^ (r & 7);
      int rr = rbase + r; if (rr >= N) rr = N - 1;
      const u16* gp = Xsrc + (size_t)rr * D128 + kb + cg * 8;
      GLD16(gp, (char*)As + ibase * 16);
      const u16* gw = Wcat + (size_t)r * 256 + k0 + cg * 8;
      GLD16(gw, (char*)Bs + ibase * 16);
    }
    __syncthreads();
#pragma unroll
    for (int kk = 0; kk < 2; ++kk) {
      bf16x8 a[4], bf[4];
      const int c = kk * 4 + chi;
#pragma unroll
      for (int m = 0; m < 4; ++m) {
        const int r = wr * 64 + m * 16 + l15;
        a[m] = *(const bf16x8*)((const char*)As + (r * 8 + (c ^ (r & 7))) * 16);
      }
#pragma unroll
      for (int n = 0; n < 4; ++n) {
        const int j = wc * 64 + n * 16 + l15;
        bf[n] = *(const bf16x8*)((const char*)Bs + (j * 8 + (c ^ (j & 7))) * 16);
      }
#pragma unroll
      for (int m = 0; m < 4; ++m)
#pragma unroll
        for (int n = 0; n < 4; ++n)
          acc[m][n] = __builtin_amdgcn_mfma_f32_16x16x32_bf16(a[m], bf[n], acc[m][n], 0, 0, 0);
    }
  }

#pragma unroll
  for (int n = 0; n < 4; ++n) {
    const int col = wc * 64 + n * 16 + l15;
    const float bv = bias[col];
#pragma unroll
    for (int m = 0; m < 4; ++m) {
      const int rb2 = rbase + wr * 64 + m * 16 + chi * 4;
#pragma unroll
      for (int q = 0; q < 4; ++q) {
        const int row = rb2 + q;
        if (row < N) {
          float vv = acc[m][n][q] + bv;
          vv = vv > 0.f ? vv : 0.f;
          io_mean[(size_t)row * D128 + col] = f2b(vv);
        }
      }
    }
  }
}

// ---------------- decoder ----------------

__global__ __launch_bounds__(256) void decoder_b_k(const u16* __restrict__ hc, const u16* __restrict__ hp,
                                                   const int* __restrict__ row, const int* __restrict__ col,
                                                   const float* __restrict__ Wd, const float* __restrict__ bd,
                                                   float* __restrict__ out, int EL) {
  int e = blockIdx.x * 4 + (threadIdx.x >> 6);
  if (e >= EL) return;
  int lane = threadIdx.x & 63;
  int l2 = lane * 2;
  int r = row[e], c = col[e];
  unsigned ua = *(const unsigned*)&hc[(size_t)r * D128 + l2];
  unsigned ub = *(const unsigned*)&hp[(size_t)c * D128 + l2];
  float ax = __uint_as_float(ua << 16), ay = __uint_as_float(ua & 0xffff0000u);
  float bx = __uint_as_float(ub << 16), by = __uint_as_float(ub & 0xffff0000u);
  float2 w0 = *(const float2*)&Wd[l2];
  float2 w1 = *(const float2*)&Wd[128 + l2];
  float p = ax * w0.x + ay * w0.y + bx * w1.x + by * w1.y;
#pragma unroll
  for (int m = 1; m < 64; m <<= 1) p += __shfl_xor(p, m, 64);
  float* xo = out + EL + (size_t)e * 256;
  float2 A; A.x = ax; A.y = ay;
  float2 B; B.x = bx; B.y = by;
  *(float2*)&xo[l2] = A;
  *(float2*)&xo[128 + l2] = B;
  if (lane == 0) out[e] = p + bd[0];
}

// ---------------- host ----------------

extern "C" void kernel_launch(void* const* d_in, const int* in_sizes, int n_in,
                              void* d_out, int out_size, void* d_ws, size_t ws_size,
                              hipStream_t stream) {
  const float* x_chem = (const float*)d_in[0];
  const float* x_prot = (const float*)d_in[1];
  const float* Wl = (const float*)d_in[2];
  const float* bl = (const float*)d_in[3];
  const float* Wr = (const float*)d_in[4];
  const float* Wd = (const float*)d_in[5];
  const float* bd = (const float*)d_in[6];
  const int* src = (const int*)d_in[7];
  const int* dst = (const int*)d_in[8];
  const int* row = (const int*)d_in[9];
  const int* col = (const int*)d_in[10];

  int NC = in_sizes[0] / D128;
  int NP = in_sizes[1] / D128;
  int E  = in_sizes[7];
  int EL = in_sizes[9];
  float* out = (float*)d_out;
  int NT = NP + NC;

  // workspace layout
  char* w = (char*)d_ws;
  size_t szC = (size_t)NC * D128 * 2;
  size_t szP = (size_t)NP * D128 * 2;
  u16* xc_bf = (u16*)w; w += szC;
  u16* xp_bf = (u16*)w; w += szP;
  u16* bufC0 = (u16*)w; w += szC;
  u16* bufC1 = (u16*)w; w += szC;
  u16* bufP0 = (u16*)w; w += szP;
  u16* bufP1 = (u16*)w; w += szP;
  u16* Wcat  = (u16*)w; w += (size_t)6 * 128 * 256 * 2;
  int* deg = (int*)w; w += (size_t)NT * 4;   // deg+cur contiguous for fused zeroing
  int* cur = (int*)w; w += (size_t)NT * 4;
  int* off = (int*)w; w += (size_t)NT * 4;
  int* bs  = (int*)w; w += 64 * 4;
  int* adj = (int*)w; w += (size_t)2 * E * 4;
  if ((size_t)(w - (char*)d_ws) > ws_size) return;

  // fused conversions + zeroing
  int n4c = NC * D128 / 4, n4p = NP * D128 / 4;
  int wq = 6 * 128 * 256 / 4;
  int zq = 2 * NT / 4;
  cvt_all_k<<<2048, 256, 0, stream>>>(x_chem, x_prot, Wl, Wr, xc_bf, xp_bf, Wcat, deg,
                                      n4c, n4p, wq, zq);

  // CSR build (combined node space)
  int gE = (E + 255) / 256;
  degree_k<<<gE, 256, 0, stream>>>(src, dst, deg, NP, E);
  int nb = (NT + 2047) / 2048;
  scan1_k<<<nb, 256, 0, stream>>>(deg, off, bs, NT);
  scan_small_k<<<1, 64, 0, stream>>>(bs, nb);
  scan_add_k<<<nb, 256, 0, stream>>>(off, bs, NT);
  fill_k<<<gE, 256, 0, stream>>>(src, dst, off, cur, adj, NP, E);

  int tilesP = (NP + 127) / 128;
  int tilesC = (NC + 127) / 128;
  const u16* hc = xc_bf;
  const u16* hp = xp_bf;
  for (int l = 0; l < 3; ++l) {
    u16* nc  = (l & 1) ? bufC1 : bufC0;
    u16* np_ = (l & 1) ? bufP1 : bufP0;
    const u16* Wc_l = Wcat + (size_t)(l * 2) * 128 * 256;
    const float* bl_l = bl + (size_t)(l * 2) * D128;
    agg_all_k<<<(NT + 3) / 4, 256, 0, stream>>>(hc, hp, nc, np_, adj, off, deg, NP, NT);
    gemm_both_k<<<tilesP + tilesC, 256, 0, stream>>>(np_, nc, hp, hc, Wc_l, bl_l, NP, NC, tilesP);
    hc = nc; hp = np_;
  }

  decoder_b_k<<<(EL + 3) / 4, 256, 0, stream>>>(hc, hp, row, col, Wd, bd, out, EL);
}